// Round 15
// baseline (146.431 us; speedup 1.0000x reference)
//
#include <hip/hip_runtime.h>

#define NEARZERO 1e-5f
#define RLEN 15
#define LOG2E 1.4426950408889634f

struct __attribute__((packed, aligned(4))) F3 { float x, y, z; };
static __device__ __forceinline__ F3 ldo(const char* base, unsigned voff) {
    return *reinterpret_cast<const F3*>(base + voff);
}

struct Par { float FC, invFC, invLPFC, K1, K2, PERC, UZL, TT, CFMAX, CFRC, CWH, C; };

static __device__ __forceinline__ void load_par(const float* sp, Par& pr,
                                                float& ra, float& rb) {
    pr.FC    = fmaf(sp[0], 950.0f, 50.0f);
    pr.K1    = fmaf(sp[1], 0.49f, 0.01f);
    pr.K2    = fmaf(sp[2], 0.199f, 0.001f);
    const float parLP = fmaf(sp[3], 0.8f, 0.2f);
    pr.PERC  = sp[4] * 10.0f;
    pr.UZL   = sp[5] * 100.0f;
    pr.TT    = fmaf(sp[6], 5.0f, -2.5f);
    pr.CFMAX = fmaf(sp[7], 9.5f, 0.5f);
    pr.CFRC  = (sp[8] * 0.1f) * pr.CFMAX;
    pr.CWH   = sp[9] * 0.2f;
    pr.C     = sp[10];
    ra       = sp[13] * 2.9f;
    rb       = sp[14] * 6.5f;
    pr.invFC   = 1.0f / pr.FC;
    pr.invLPFC = 1.0f / (parLP * pr.FC);
}

static __device__ __forceinline__ void make_w(float ra, float rb, float (&w)[RLEN]) {
    const float aa    = fmaxf(ra, 0.0f) + 0.1f;
    const float theta = fmaxf(rb, 0.0f) + 0.5f;
    const float am1   = aa - 1.0f;
    const float nitl2 = -LOG2E / theta;
    float wsum = 0.0f;
#pragma unroll
    for (int k = 0; k < RLEN; ++k) {
        const float tk = (float)k + 0.5f;
        w[k] = exp2f(am1 * __log2f(tk) + tk * nitl2);
        wsum += w[k];
    }
    const float winv = 1.0f / wsum;
#pragma unroll
    for (int k = 0; k < RLEN; ++k) w[k] *= winv;
}

// prologue-only: snow+soil of t=0 for one cell
__device__ __forceinline__ void ab_step(
    const F3& f, const F3& d3, const Par& pr,
    float& SP, float& MW, float& SM, float& SLZ,
    float cs, float& rxP, float& k0P)
{
    const float dT   = f.y - pr.TT;
    const float RAIN = (dT >= 0.0f) ? f.x : 0.0f;
    SP += f.x - RAIN;
    const float melt = __builtin_amdgcn_fmed3f(pr.CFMAX * dT, 0.0f, SP);
    MW += melt;  SP -= melt;
    const float refr = __builtin_amdgcn_fmed3f(pr.CFRC * (0.0f - dT), 0.0f, MW);
    SP += refr;  MW -= refr;
    const float tosoil = fmaxf(fmaf(-pr.CWH, SP, MW), 0.0f);
    MW -= tosoil;
    const float sw = fminf(exp2f(fmaf(d3.x, 5.0f, 1.0f) * __log2f(SM * pr.invFC)), 1.0f);
    const float rt = RAIN + tosoil;
    const float rc = rt * sw;
    SM = fmaf(rt, 1.0f - sw, SM);
    const float ex = fmaxf(SM - pr.FC, 0.0f);
    SM = fminf(SM, pr.FC);
    const float ef = fminf(exp2f(fmaf(d3.z, 4.7f, 0.3f) * __log2f(SM * pr.invLPFC)), 1.0f);
    SM = fmaxf(SM - f.z * ef, NEARZERO);
    const float cap = cs * (1.0f - fminf(SM * pr.invFC, 1.0f));
    SM  = fmaxf(SM + cap, NEARZERO);
    SLZ = fmaxf(SLZ - cap, NEARZERO);
    rxP = rc + ex;
    k0P = fmaf(d3.y, 0.85f, 0.05f);
}

// fused pair-iteration: finish(m) + ab(m+1) for TWO independent cells,
// section-interleaved so each trans latency is covered by the other cell.
template<int PH>
__device__ __forceinline__ void fused2(
    const F3 fA, const F3 dA, const F3 fB, const F3 dB,
    const Par& pA, const Par& pB,
    float& SPa, float& MWa, float& SMa, float& SUa, float& SLa,
    float& SPb, float& MWb, float& SMb, float& SUb, float& SLb,
    float& rxA, float& k0A, float& rxB, float& k0B,
    float (&accA)[RLEN], float (&accB)[RLEN],
    const float (&wA)[RLEN], const float (&wB)[RLEN],
    float* oA, float* oB, bool guard)
{
    // trans #1 (both spines) first: SM(m) ready now
    const float t1A = __log2f(SMa * pA.invFC);
    const float t1B = __log2f(SMb * pB.invFC);
    // snow(m+1) A,B — independent of t1
    const float dTA = fA.y - pA.TT;               const float dTB = fB.y - pB.TT;
    const float RNA = (dTA >= 0.0f) ? fA.x : 0.0f;
    const float RNB = (dTB >= 0.0f) ? fB.x : 0.0f;
    SPa += fA.x - RNA;                            SPb += fB.x - RNB;
    const float mlA = __builtin_amdgcn_fmed3f(pA.CFMAX * dTA, 0.0f, SPa);
    const float mlB = __builtin_amdgcn_fmed3f(pB.CFMAX * dTB, 0.0f, SPb);
    MWa += mlA;  SPa -= mlA;                      MWb += mlB;  SPb -= mlB;
    const float rfA = __builtin_amdgcn_fmed3f(pA.CFRC * (0.0f - dTA), 0.0f, MWa);
    const float rfB = __builtin_amdgcn_fmed3f(pB.CFRC * (0.0f - dTB), 0.0f, MWb);
    SPa += rfA;  MWa -= rfA;                      SPb += rfB;  MWb -= rfB;
    const float tsA = fmaxf(fmaf(-pA.CWH, SPa, MWa), 0.0f);
    const float tsB = fmaxf(fmaf(-pB.CWH, SPb, MWb), 0.0f);
    MWa -= tsA;                                   MWb -= tsB;
    // finish(m) upper zone A,B — independent
    SUa += rxA;                                   SUb += rxB;
    const float PCa = fminf(SUa, pA.PERC);        const float PCb = fminf(SUb, pB.PERC);
    SUa -= PCa;                                   SUb -= PCb;
    const float Q0a = k0A * fmaxf(SUa - pA.UZL, 0.0f);
    const float Q0b = k0B * fmaxf(SUb - pB.UZL, 0.0f);
    SUa -= Q0a;                                   SUb -= Q0b;
    const float Q1a = pA.K1 * SUa;                const float Q1b = pB.K1 * SUb;
    SUa -= Q1a;                                   SUb -= Q1b;
    // trans #2 (t1 long ready)
    const float swA = fminf(exp2f(fmaf(dA.x, 5.0f, 1.0f) * t1A), 1.0f);
    const float swB = fminf(exp2f(fmaf(dB.x, 5.0f, 1.0f) * t1B), 1.0f);
    // finish(m) lower zone A,B
    SLa += PCa;                                   SLb += PCb;
    const float Q2a = pA.K2 * SLa;                const float Q2b = pB.K2 * SLb;
    SLa -= Q2a;                                   SLb -= Q2b;
    const float Qsa = Q0a + Q1a + Q2a;            const float Qsb = Q0b + Q1b + Q2b;
    const float csA = pA.C * SLa;                 const float csB = pB.C * SLb;
    // soil mid A,B (sw ready)
    const float rtA = RNA + tsA;                  const float rtB = RNB + tsB;
    const float rcA = rtA * swA;                  const float rcB = rtB * swB;
    SMa = fmaf(rtA, 1.0f - swA, SMa);             SMb = fmaf(rtB, 1.0f - swB, SMb);
    const float exA = fmaxf(SMa - pA.FC, 0.0f);   const float exB = fmaxf(SMb - pB.FC, 0.0f);
    SMa = fminf(SMa, pA.FC);                      SMb = fminf(SMb, pB.FC);
    // trans #3
    const float t2A = __log2f(SMa * pA.invLPFC);
    const float t2B = __log2f(SMb * pB.invLPFC);
    // FIR(m) A,B + stores — 30 independent FMAs hide t2
    const float qrA = fmaf(wA[0], Qsa, accA[PH]);
    const float qrB = fmaf(wB[0], Qsb, accB[PH]);
    accA[PH] = 0.0f;                              accB[PH] = 0.0f;
#pragma unroll
    for (int k = 1; k < RLEN; ++k) {
        const int j = (PH + k) % RLEN;            // compile-time
        accA[j] = fmaf(wA[k], Qsa, accA[j]);
        accB[j] = fmaf(wB[k], Qsb, accB[j]);
    }
    if (guard) {
        __builtin_nontemporal_store(qrA, oA);
        __builtin_nontemporal_store(qrB, oB);
    }
    // trans #4 + soil tail A,B
    const float efA = fminf(exp2f(fmaf(dA.z, 4.7f, 0.3f) * t2A), 1.0f);
    const float efB = fminf(exp2f(fmaf(dB.z, 4.7f, 0.3f) * t2B), 1.0f);
    SMa = fmaxf(SMa - fA.z * efA, NEARZERO);      SMb = fmaxf(SMb - fB.z * efB, NEARZERO);
    const float cpA = csA * (1.0f - fminf(SMa * pA.invFC, 1.0f));
    const float cpB = csB * (1.0f - fminf(SMb * pB.invFC, 1.0f));
    SMa = fmaxf(SMa + cpA, NEARZERO);             SMb = fmaxf(SMb + cpB, NEARZERO);
    SLa = fmaxf(SLa - cpA, NEARZERO);             SLb = fmaxf(SLb - cpB, NEARZERO);
    rxA = rcA + exA;                              rxB = rcB + exB;
    k0A = fmaf(dA.y, 0.85f, 0.05f);               k0B = fmaf(dB.y, 0.85f, 0.05f);
}

// final step's zones+FIR head+store only (one cell)
template<int PH>
__device__ __forceinline__ void finish_last(
    const Par& pr, float& SUZ, float& SLZ, float rxP, float k0P,
    float (&acc)[RLEN], const float (&w)[RLEN], float* outp, bool guard)
{
    SUZ += rxP;
    const float PERCv = fminf(SUZ, pr.PERC);
    SUZ -= PERCv;
    const float Q0 = k0P * fmaxf(SUZ - pr.UZL, 0.0f);
    SUZ -= Q0;
    const float Q1 = pr.K1 * SUZ;
    SUZ -= Q1;
    SLZ += PERCv;
    const float Q2 = pr.K2 * SLZ;
    SLZ -= Q2;
    const float Qs = Q0 + Q1 + Q2;
    const float qr = fmaf(w[0], Qs, acc[PH]);
    if (guard) __builtin_nontemporal_store(qr, outp);
}

__global__ __launch_bounds__(256, 1)
void hbv_kernel(const float* __restrict__ forcing,   // (365,G,3)
                const float* __restrict__ dynr,      // (365,G,3)
                const float* __restrict__ statr,     // (G,15)
                float* __restrict__ out,             // (365,G)
                int G, int half)
{
    const int g = blockIdx.x * 256 + threadIdx.x;
    const bool guard = (g < half);
    const int gA = guard ? g : (half - 1);           // clamp; stores guarded
    const int gB = gA + half;                        // < G (G even)

    // ---- per-cell params + FIR weights ----
    Par pA, pB; float raA, rbA, raB, rbB;
    load_par(statr + (size_t)gA * 15, pA, raA, rbA);
    load_par(statr + (size_t)gB * 15, pB, raB, rbB);
    float wA[RLEN], wB[RLEN];
    make_w(raA, rbA, wA);
    make_w(raB, rbB, wB);

    // ---- state ----
    float SPa = 0.001f, MWa = 0.001f, SMa = 0.001f, SUa = 0.001f, SLa = 0.001f;
    float SPb = 0.001f, MWb = 0.001f, SMb = 0.001f, SUb = 0.001f, SLb = 0.001f;
    float accA[RLEN], accB[RLEN];
#pragma unroll
    for (int k = 0; k < RLEN; ++k) { accA[k] = 0.0f; accB[k] = 0.0f; }
    float rxA = 0.0f, k0A = 0.0f, rxB = 0.0f, k0B = 0.0f;

    // ---- addressing: uniform base + 32-bit running voffsets ----
    const char* fbase = (const char*)forcing;
    const char* dbase = (const char*)dynr;
    char*       obase = (char*)out;
    const unsigned G12 = (unsigned)G * 12u;
    const unsigned G4  = (unsigned)G * 4u;
    const unsigned HB4 = (unsigned)half * 4u;
    unsigned vA = (unsigned)gA * 12u;                // cell A, row 0
    unsigned vB = (unsigned)gB * 12u;                // cell B, row 0
    unsigned vO = (unsigned)g * 4u;                  // out row 0 (lane g)

    // ---- depth-3 register ring per cell (3 | 15 -> slot = (m+1) % 3) ----
    F3 bFA[3], bDA[3], bFB[3], bDB[3];
#pragma unroll
    for (int r = 0; r < 3; ++r) {
        bFA[r] = ldo(fbase, vA); bDA[r] = ldo(dbase, vA);
        bFB[r] = ldo(fbase, vB); bDB[r] = ldo(dbase, vB);
        vA += G12; vB += G12;
    }                                                // vA,vB now at row 3

    // ---- prologue: ab(0) both cells; restage row 3 -> slot 0 ----
    {
        const float cs0A = pA.C * SLa, cs0B = pB.C * SLb;
        const F3 fA_ = bFA[0], dA_ = bDA[0], fB_ = bFB[0], dB_ = bDB[0];
        bFA[0] = ldo(fbase, vA); bDA[0] = ldo(dbase, vA);
        bFB[0] = ldo(fbase, vB); bDB[0] = ldo(dbase, vB);
        vA += G12; vB += G12;
        __builtin_amdgcn_sched_barrier(0x7);         // pin VMEM; ALU may cross
        ab_step(fA_, dA_, pA, SPa, MWa, SMa, SLa, cs0A, rxA, k0A);
        ab_step(fB_, dB_, pB, SPb, MWb, SMb, SLb, cs0B, rxB, k0B);
    }

    // Iteration m: consume row m+1 (slot (m+1)%3), stage row m+4 (same slot),
    // run fused2<m%15> = finish(m) + ab(m+1), both cells.
#define ITER(MM, VLA, VLB, DOLOAD) do { \
    constexpr int PH_ = (MM) % RLEN; \
    constexpr int S_  = ((MM) + 1) % 3; \
    const F3 fA_ = bFA[S_], dA_ = bDA[S_], fB_ = bFB[S_], dB_ = bDB[S_]; \
    if (DOLOAD) { \
        bFA[S_] = ldo(fbase, (VLA)); bDA[S_] = ldo(dbase, (VLA)); \
        bFB[S_] = ldo(fbase, (VLB)); bDB[S_] = ldo(dbase, (VLB)); \
    } \
    __builtin_amdgcn_sched_barrier(0x7); \
    fused2<PH_>(fA_, dA_, fB_, dB_, pA, pB, \
                SPa, MWa, SMa, SUa, SLa, SPb, MWb, SMb, SUb, SLb, \
                rxA, k0A, rxB, k0B, accA, accB, wA, wB, \
                (float*)(obase + vO), (float*)(obase + vO + HB4), guard); \
    vO += G4; \
} while (0)

#define ITERADV(MM) do { ITER(MM, vA, vB, true); vA += G12; vB += G12; } while (0)

    // ---- main: m = 0..359 (24 x 15); stages rows 4..363 ----
    for (int i = 0; i < 24; ++i) {
        ITERADV(0);  ITERADV(1);  ITERADV(2);  ITERADV(3);  ITERADV(4);
        ITERADV(5);  ITERADV(6);  ITERADV(7);  ITERADV(8);  ITERADV(9);
        ITERADV(10); ITERADV(11); ITERADV(12); ITERADV(13); ITERADV(14);
    }
    // ---- m=360: stage row 364 (last real) ----
    ITER(0, vA, vB, true);
    // ---- m=361..363: consume rows 362..364, no load ----
    ITER(1, 0u, 0u, false);
    ITER(2, 0u, 0u, false);
    ITER(3, 0u, 0u, false);
    // ---- final: finish(364), phase 4, both cells ----
    finish_last<4>(pA, SUa, SLa, rxA, k0A, accA, wA, (float*)(obase + vO), guard);
    finish_last<4>(pB, SUb, SLb, rxB, k0B, accB, wB, (float*)(obase + vO + HB4), guard);
#undef ITERADV
#undef ITER
}

extern "C" void kernel_launch(void* const* d_in, const int* in_sizes, int n_in,
                              void* d_out, int out_size, void* d_ws, size_t ws_size,
                              hipStream_t stream) {
    const float* forcing = (const float*)d_in[0];
    const float* dynr    = (const float*)d_in[1];
    const float* statr   = (const float*)d_in[2];
    float* out = (float*)d_out;

    const int G    = in_sizes[2] / 15;       // static_raw (G,15); T fixed at 365
    const int half = G / 2;                  // G = 50000 (even): A=[0,half), B=[half,G)
    const int block = 256;
    const int grid  = (half + block - 1) / block;   // 98 blocks = 392 waves, co-resident
    hbv_kernel<<<grid, block, 0, stream>>>(forcing, dynr, statr, out, G, half);
}

// Round 16
// 115.165 us; speedup vs baseline: 1.2715x; 1.2715x over previous
//
#include <hip/hip_runtime.h>

#define NEARZERO 1e-5f
#define RLEN 15
#define LOG2E 1.4426950408889634f

struct __attribute__((packed, aligned(4))) F3 { float x, y, z; };
static __device__ __forceinline__ F3 ldo(const char* base, unsigned voff) {
    return *reinterpret_cast<const F3*>(base + voff);
}

struct Par { float FC, invFC, invLPFC, K1, K2, PERC, UZL, TT, CFMAX, nCFRC, nCWH, C; };

// prologue-only: snow+soil of t=0
__device__ __forceinline__ void ab_step(
    const F3& f, const F3& d3, const Par& pr,
    float& SP, float& MW, float& SM, float& SLZ,
    float cs, float& rxP, float& k0P)
{
    const float dT   = f.y - pr.TT;
    const float SNOW = (dT >= 0.0f) ? 0.0f : f.x;
    const float RAIN = f.x - SNOW;
    SP += SNOW;
    const float melt = __builtin_amdgcn_fmed3f(pr.CFMAX * dT, 0.0f, SP);
    MW += melt;  SP -= melt;
    const float refr = __builtin_amdgcn_fmed3f(pr.nCFRC * dT, 0.0f, MW);
    SP += refr;  MW -= refr;
    const float tosoil = fmaxf(fmaf(pr.nCWH, SP, MW), 0.0f);
    MW -= tosoil;
    const float sw = fminf(exp2f(fmaf(d3.x, 5.0f, 1.0f) * __log2f(SM * pr.invFC)), 1.0f);
    const float rt = RAIN + tosoil;
    const float rc = rt * sw;
    SM = fmaf(rt, 1.0f - sw, SM);
    const float ex = fmaxf(SM - pr.FC, 0.0f);
    SM = fminf(SM, pr.FC);
    const float ef = fminf(exp2f(fmaf(d3.z, 4.7f, 0.3f) * __log2f(SM * pr.invLPFC)), 1.0f);
    SM = fmaxf(fmaf(-f.z, ef, SM), NEARZERO);
    const float u  = fminf(SM * pr.invFC, 1.0f);
    const float cap = fmaf(-cs, u, cs);
    SM  = fmaxf(SM + cap, NEARZERO);
    SLZ = fmaxf(SLZ - cap, NEARZERO);
    rxP = rc + ex;
    k0P = fmaf(d3.y, 0.85f, 0.05f);
}

// fused iteration m: finish(m) [zones+FIR+store] skew-interleaved with ab(m+1).
template<int PH>
__device__ __forceinline__ void fused_iter(
    const F3 f, const F3 d3, const Par& pr,
    float& SP, float& MW, float& SM, float& SUZ, float& SLZ,
    float& rxP, float& k0P,
    float (&acc)[RLEN], const float (&w)[RLEN],
    float* outp)
{
    // trans #1: SM(m) ready at entry
    const float t1 = __log2f(SM * pr.invFC);
    // snow(m+1)
    const float dT   = f.y - pr.TT;
    const float SNOW = (dT >= 0.0f) ? 0.0f : f.x;
    const float RAIN = f.x - SNOW;
    SP += SNOW;
    const float melt = __builtin_amdgcn_fmed3f(pr.CFMAX * dT, 0.0f, SP);
    MW += melt;  SP -= melt;
    const float refr = __builtin_amdgcn_fmed3f(pr.nCFRC * dT, 0.0f, MW);
    SP += refr;  MW -= refr;
    const float tosoil = fmaxf(fmaf(pr.nCWH, SP, MW), 0.0f);
    MW -= tosoil;
    // finish(m) upper zone (SSA-folded)
    const float a  = SUZ + rxP;
    const float PERCv = fminf(a, pr.PERC);
    const float b  = a - PERCv;
    const float Q0 = k0P * fmaxf(b - pr.UZL, 0.0f);
    const float c  = b - Q0;
    const float Q1 = pr.K1 * c;
    SUZ = c - Q1;
    // trans #2
    const float sw = fminf(exp2f(fmaf(d3.x, 5.0f, 1.0f) * t1), 1.0f);
    const float rt = RAIN + tosoil;
    // finish(m) lower zone
    const float dz = SLZ + PERCv;
    const float Q2 = pr.K2 * dz;
    SLZ = dz - Q2;
    const float cs = pr.C * SLZ;
    const float Qs = (Q0 + Q1) + Q2;
    // soil mid (m+1)
    const float rc = rt * sw;
    SM = fmaf(rt, 1.0f - sw, SM);
    const float ex = fmaxf(SM - pr.FC, 0.0f);
    SM = fminf(SM, pr.FC);
    // trans #3 (hidden under FIR)
    const float t2 = __log2f(SM * pr.invLPFC);
    // FIR(m) + store (unguarded: OOB threads returned at kernel entry)
    const float qr = fmaf(w[0], Qs, acc[PH]);
    acc[PH] = 0.0f;
#pragma unroll
    for (int k = 1; k < RLEN; ++k) {
        const int j = (PH + k) % RLEN;           // compile-time
        acc[j] = fmaf(w[k], Qs, acc[j]);
    }
    __builtin_nontemporal_store(qr, outp);
    // trans #4 + soil tail (m+1)
    const float ef = fminf(exp2f(fmaf(d3.z, 4.7f, 0.3f) * t2), 1.0f);
    SM = fmaxf(fmaf(-f.z, ef, SM), NEARZERO);
    const float u  = fminf(SM * pr.invFC, 1.0f);
    const float cap = fmaf(-cs, u, cs);          // cs*(1-u), single fma
    SM  = fmaxf(SM + cap, NEARZERO);
    SLZ = fmaxf(SLZ - cap, NEARZERO);
    rxP = rc + ex;
    k0P = fmaf(d3.y, 0.85f, 0.05f);
}

// final step's zones+FIR head+store only
template<int PH>
__device__ __forceinline__ void finish_last(
    const Par& pr, float& SUZ, float& SLZ, float rxP, float k0P,
    float (&acc)[RLEN], const float (&w)[RLEN], float* outp)
{
    const float a  = SUZ + rxP;
    const float PERCv = fminf(a, pr.PERC);
    const float b  = a - PERCv;
    const float Q0 = k0P * fmaxf(b - pr.UZL, 0.0f);
    const float c  = b - Q0;
    const float Q1 = pr.K1 * c;
    const float dz = SLZ + PERCv;
    const float Q2 = pr.K2 * dz;
    const float Qs = (Q0 + Q1) + Q2;
    const float qr = fmaf(w[0], Qs, acc[PH]);
    __builtin_nontemporal_store(qr, outp);
}

__global__ __launch_bounds__(256, 1)
void hbv_kernel(const float* __restrict__ forcing,   // (365,G,3)
                const float* __restrict__ dynr,      // (365,G,3)
                const float* __restrict__ statr,     // (G,15)
                float* __restrict__ out,             // (365,G)
                int G)
{
    const int g = blockIdx.x * 256 + threadIdx.x;
    if (g >= G) return;                // exec permanently masked for OOB lanes:
                                       // no per-step guard, no clamps below.

    // ---- static parameters ----
    const float* sp = statr + (size_t)g * 15;
    Par pr;
    pr.FC    = fmaf(sp[0], 950.0f, 50.0f);
    pr.K1    = fmaf(sp[1], 0.49f, 0.01f);
    pr.K2    = fmaf(sp[2], 0.199f, 0.001f);
    const float parLP = fmaf(sp[3], 0.8f, 0.2f);
    pr.PERC  = sp[4] * 10.0f;
    pr.UZL   = sp[5] * 100.0f;
    pr.TT    = fmaf(sp[6], 5.0f, -2.5f);
    pr.CFMAX = fmaf(sp[7], 9.5f, 0.5f);
    pr.nCFRC = -(sp[8] * 0.1f) * pr.CFMAX;
    pr.nCWH  = -(sp[9] * 0.2f);
    pr.C     = sp[10];
    const float rout_a = sp[13] * 2.9f;
    const float rout_b = sp[14] * 6.5f;
    pr.invFC   = 1.0f / pr.FC;
    pr.invLPFC = 1.0f / (parLP * pr.FC);

    // ---- routing weights (Gamma(aa)*theta^aa cancels in normalization) ----
    const float aa    = fmaxf(rout_a, 0.0f) + 0.1f;
    const float theta = fmaxf(rout_b, 0.0f) + 0.5f;
    const float am1   = aa - 1.0f;
    const float nitl2 = -LOG2E / theta;
    float w[RLEN];
    float wsum = 0.0f;
#pragma unroll
    for (int k = 0; k < RLEN; ++k) {
        const float tk = (float)k + 0.5f;
        w[k] = exp2f(am1 * __log2f(tk) + tk * nitl2);
        wsum += w[k];
    }
    const float winv = 1.0f / wsum;
#pragma unroll
    for (int k = 0; k < RLEN; ++k) w[k] *= winv;

    // ---- state ----
    float SP_ = 0.001f, MW = 0.001f, SM = 0.001f, SUZ = 0.001f, SLZ = 0.001f;
    float acc[RLEN];
#pragma unroll
    for (int k = 0; k < RLEN; ++k) acc[k] = 0.0f;
    float rxP = 0.0f, k0P = 0.0f;

    // ---- uniform-base + 32-bit running voffsets ----
    const char* fbase = (const char*)forcing;
    const char* dbase = (const char*)dynr;
    char*       obase = (char*)out;
    const unsigned G12 = (unsigned)G * 12u;
    const unsigned G4  = (unsigned)G * 4u;
    unsigned vRun = (unsigned)g * 12u;             // row 0
    unsigned vO   = (unsigned)g * 4u;              // out row 0

    // ---- depth-3 register ring (3 | 15 -> slot = (m+1) % 3, constexpr) ----
    F3 bF[3], bD[3];
#pragma unroll
    for (int r = 0; r < 3; ++r) {
        bF[r] = ldo(fbase, vRun); bD[r] = ldo(dbase, vRun);
        vRun += G12;
    }                                               // vRun at row 3

    // ---- prologue: ab(0); restage row 3 -> slot 0 ----
    {
        const float cs0 = pr.C * SLZ;
        const F3 f_ = bF[0], d_ = bD[0];
        bF[0] = ldo(fbase, vRun); bD[0] = ldo(dbase, vRun);
        vRun += G12;
        __builtin_amdgcn_sched_barrier(0x7);        // pin VMEM; ALU may cross
        ab_step(f_, d_, pr, SP_, MW, SM, SLZ, cs0, rxP, k0P);
    }

    // Iter m: consume row m+1 (slot (m+1)%3), stage row m+4 into same slot,
    // run fused_iter<m%15> = finish(m) + ab(m+1).
#define ITER(MM, DOLOAD) do { \
    constexpr int PH_ = (MM) % RLEN; \
    constexpr int S_  = ((MM) + 1) % 3; \
    const F3 f_ = bF[S_], d_ = bD[S_]; \
    if (DOLOAD) { \
        bF[S_] = ldo(fbase, vRun); bD[S_] = ldo(dbase, vRun); \
        vRun += G12; \
    } \
    __builtin_amdgcn_sched_barrier(0x7); \
    fused_iter<PH_>(f_, d_, pr, SP_, MW, SM, SUZ, SLZ, rxP, k0P, acc, w, \
                    (float*)(obase + vO)); \
    vO += G4; \
} while (0)

    // ---- main: m = 0..359 (24 x 15); stages rows 4..363 ----
    for (int i = 0; i < 24; ++i) {
        ITER(0, true);  ITER(1, true);  ITER(2, true);  ITER(3, true);  ITER(4, true);
        ITER(5, true);  ITER(6, true);  ITER(7, true);  ITER(8, true);  ITER(9, true);
        ITER(10, true); ITER(11, true); ITER(12, true); ITER(13, true); ITER(14, true);
    }
    // ---- m=360: stages row 364 (last real) ----
    ITER(0, true);
    // ---- m=361..363: consume rows 362..364, no load ----
    ITER(1, false);
    ITER(2, false);
    ITER(3, false);
    // ---- final: finish(364), phase 364 % 15 = 4 ----
    finish_last<4>(pr, SUZ, SLZ, rxP, k0P, acc, w, (float*)(obase + vO));
#undef ITER
}

extern "C" void kernel_launch(void* const* d_in, const int* in_sizes, int n_in,
                              void* d_out, int out_size, void* d_ws, size_t ws_size,
                              hipStream_t stream) {
    const float* forcing = (const float*)d_in[0];
    const float* dynr    = (const float*)d_in[1];
    const float* statr   = (const float*)d_in[2];
    float* out = (float*)d_out;

    const int G = in_sizes[2] / 15;          // static_raw (G,15); T fixed at 365
    const int block = 256;
    const int grid  = (G + block - 1) / block;
    hbv_kernel<<<grid, block, 0, stream>>>(forcing, dynr, statr, out, G);
}